// Round 3
// baseline (374.475 us; speedup 1.0000x reference)
//
#include <hip/hip_runtime.h>

// APG_Linear: out[b] = ((inp[b] @ U) @ W_b) @ V + bias
//   B=131072, IN=128, OUT=128, RANK=32, all f32. Memory-bound (671 MB).
// R2: take h2 path off the LDS pipe:
//   - step 2 via column-major W loads (16 dword loads/lane, coalesced
//     2x128B segments) -> pure per-lane FMA + one xor-32; kills the 12-op
//     h2 shuffle reduction.
//   - step 3 broadcasts via explicit v_readlane (VALU, not ds_bpermute).
//   - GRID 2048 to shrink the occupancy tail.

constexpr int RANK  = 32;
constexpr int BLOCK = 256;            // 4 waves/block
constexpr int WPB   = BLOCK / 64;
constexpr int GRID  = 2048;
constexpr int NWAVES = GRID * WPB;    // 8192 waves -> 16 rows/wave at B=131072

__device__ __forceinline__ float bcast(float v, int srclane) {
    return __uint_as_float(__builtin_amdgcn_readlane(__float_as_uint(v), srclane));
}

__global__ __launch_bounds__(BLOCK, 3)
void apg_linear_kernel(const float* __restrict__ inp,
                       const float* __restrict__ gw,
                       const float* __restrict__ U,
                       const float* __restrict__ V,
                       const float* __restrict__ bias,
                       float* __restrict__ out,
                       int nrows)
{
    __shared__ float4 u4s[1024];        // U staged: 128x32 f32 = 16 KiB
    __shared__ float  hbuf[WPB][RANK];  // per-wave h park (128 B each)

    const int tid  = threadIdx.x;
    const int lane = tid & 63;
    const int wid  = tid >> 6;
    const int g    = lane >> 3;         // 0..7
    const int o    = lane & 31;         // h2 output owned by this lane
    const int half = lane >> 5;         // k-half for step 2

    // ---- stage U into LDS (flat float4 layout: u4s[f] = U[4f..4f+3]) ----
    #pragma unroll
    for (int j = 0; j < 4; ++j)
        u4s[j * BLOCK + tid] = reinterpret_cast<const float4*>(U)[j * BLOCK + tid];
    __syncthreads();

    // ---- V and bias in registers: lane owns output cols {2*lane, 2*lane+1} ----
    float2 v2[RANK];
    #pragma unroll
    for (int r = 0; r < RANK; ++r)
        v2[r] = reinterpret_cast<const float2*>(V + r * 128)[lane];
    const float2 b2 = reinterpret_cast<const float2*>(bias)[lane];

    float* hw = hbuf[wid];

    const int wave0 = blockIdx.x * WPB + wid;
    const int iters = (nrows + NWAVES - 1) / NWAVES;   // 16 at B=131072

    int row = wave0;
    // ---- prefetch row 0 ----
    float x0n = 0.f, x1n = 0.f;
    float wcn[16];
    #pragma unroll
    for (int kk = 0; kk < 16; ++kk) wcn[kk] = 0.f;
    if (row < nrows) {
        x0n = inp[row * 128 + lane];
        x1n = inp[row * 128 + 64 + lane];
        const float* wb = gw + row * 1024 + half * 512 + o;   // W[half*16+kk][o]
        #pragma unroll
        for (int kk = 0; kk < 16; ++kk) wcn[kk] = wb[kk * 32];
    }

    for (int it = 0; it < iters; ++it) {
        if (row >= nrows) break;
        const float x0 = x0n, x1 = x1n;
        float wc[16];
        #pragma unroll
        for (int kk = 0; kk < 16; ++kk) wc[kk] = wcn[kk];

        // ---- prefetch next row (overlaps with compute below) ----
        const int nrow = row + NWAVES;
        if (it + 1 < iters && nrow < nrows) {
            x0n = inp[nrow * 128 + lane];
            x1n = inp[nrow * 128 + 64 + lane];
            const float* wb = gw + nrow * 1024 + half * 512 + o;
            #pragma unroll
            for (int kk = 0; kk < 16; ++kk) wcn[kk] = wb[kk * 32];
        }

        // ---- step 1: h = inp_row @ U -------------------------------------
        // lane accumulates h[4c..4c+3] (c = lane&7) over i = t*8+g, t=0..15
        float h1a[4] = {0.f, 0.f, 0.f, 0.f};
        #pragma unroll
        for (int t = 0; t < 16; ++t) {
            const float xs = (t < 8) ? x0 : x1;            // t is constant
            const float xi = __shfl(xs, (t & 7) * 8 + g, 64);
            const float4 u = u4s[t * 64 + lane];
            h1a[0] = fmaf(xi, u.x, h1a[0]);
            h1a[1] = fmaf(xi, u.y, h1a[1]);
            h1a[2] = fmaf(xi, u.z, h1a[2]);
            h1a[3] = fmaf(xi, u.w, h1a[3]);
        }
        #pragma unroll
        for (int s = 8; s <= 32; s <<= 1) {
            #pragma unroll
            for (int k = 0; k < 4; ++k)
                h1a[k] += __shfl_xor(h1a[k], s, 64);
        }
        // park h in per-wave LDS (lane group c holds h[4c..4c+3])
        if (lane < 8)
            reinterpret_cast<float4*>(hw)[lane] =
                make_float4(h1a[0], h1a[1], h1a[2], h1a[3]);

        // ---- step 2: h2[o] = sum_k h[k] * W[k][o], k split by halves -----
        float h2 = 0.f;
        #pragma unroll
        for (int t = 0; t < 4; ++t) {
            // broadcast read: 32 lanes same address per half, conflict-free
            const float4 h4 = reinterpret_cast<const float4*>(hw)[half * 4 + t];
            h2 = fmaf(h4.x, wc[t * 4 + 0], h2);
            h2 = fmaf(h4.y, wc[t * 4 + 1], h2);
            h2 = fmaf(h4.z, wc[t * 4 + 2], h2);
            h2 = fmaf(h4.w, wc[t * 4 + 3], h2);
        }
        h2 += __shfl_xor(h2, 32, 64);   // combine k-halves; lane l holds h2[l&31]

        // ---- step 3: out_row = h2 @ V + bias (readlane broadcasts) -------
        float o0 = b2.x, o1 = b2.y;
        #pragma unroll
        for (int k = 0; k < RANK; ++k) {
            const float h2k = bcast(h2, k);
            o0 = fmaf(h2k, v2[k].x, o0);
            o1 = fmaf(h2k, v2[k].y, o1);
        }
        reinterpret_cast<float2*>(out)[row * 64 + lane] = make_float2(o0, o1);

        row = nrow;
    }
}

extern "C" void kernel_launch(void* const* d_in, const int* in_sizes, int n_in,
                              void* d_out, int out_size, void* d_ws, size_t ws_size,
                              hipStream_t stream)
{
    const float* inp  = (const float*)d_in[0];
    const float* gw   = (const float*)d_in[1];
    const float* U    = (const float*)d_in[2];
    const float* V    = (const float*)d_in[3];
    const float* bias = (const float*)d_in[4];
    float* out = (float*)d_out;
    const int nrows = in_sizes[0] / 128;   // B = 131072

    apg_linear_kernel<<<GRID, BLOCK, 0, stream>>>(inp, gw, U, V, bias, out, nrows);
}

// Round 4
// 132.022 us; speedup vs baseline: 2.8365x; 2.8365x over previous
//
#include <hip/hip_runtime.h>

// APG_Linear: out[b] = ((inp[b] @ U) @ W_b) @ V + bias
//   B=131072, IN=128, OUT=128, RANK=32, all f32. Memory-bound (671 MB).
// R3 = R1 structure (known-good 140.9 us) with ONE change:
//   step-3 broadcasts via v_readlane (SALU) instead of __shfl (ds_bpermute),
//   removing 32 LDS-pipe ops/row (93 -> 61 ops, ~650 -> ~430 cy/row,
//   now under the 478 cy/row per-CU HBM pace).
// R2's column-load scheme regressed 2.7x: VGPR collapsed to 84 (< the 96+
// live values) -> compiler demoted state; FETCH +148 MB / WRITE +80 MB of
// spill traffic. Reverted.

constexpr int RANK  = 32;
constexpr int BLOCK = 256;            // 4 waves/block
constexpr int WPB   = BLOCK / 64;
constexpr int GRID  = 1024;
constexpr int NWAVES = GRID * WPB;    // 4096 waves -> 32 rows/wave at B=131072

__device__ __forceinline__ float bcast(float v, int srclane) {
    return __uint_as_float(__builtin_amdgcn_readlane(__float_as_uint(v), srclane));
}

__global__ __launch_bounds__(BLOCK, 2)
void apg_linear_kernel(const float* __restrict__ inp,
                       const float* __restrict__ gw,
                       const float* __restrict__ U,
                       const float* __restrict__ V,
                       const float* __restrict__ bias,
                       float* __restrict__ out,
                       int nrows)
{
    __shared__ float4 u4s[1024];        // U staged: 128x32 f32 = 16 KiB
    __shared__ float  hbuf[WPB][RANK];  // per-wave h park (128 B each)

    const int tid  = threadIdx.x;
    const int lane = tid & 63;
    const int wid  = tid >> 6;
    const int g    = lane >> 3;         // 0..7

    // ---- stage U into LDS (flat float4 layout: u4s[f] = U[4f..4f+3]) ----
    #pragma unroll
    for (int j = 0; j < 4; ++j)
        u4s[j * BLOCK + tid] = reinterpret_cast<const float4*>(U)[j * BLOCK + tid];
    __syncthreads();

    // ---- V and bias in registers: lane owns output cols {2*lane, 2*lane+1} ----
    float2 v2[RANK];
    #pragma unroll
    for (int r = 0; r < RANK; ++r)
        v2[r] = reinterpret_cast<const float2*>(V + r * 128)[lane];
    const float2 b2 = reinterpret_cast<const float2*>(bias)[lane];

    float* hw = hbuf[wid];

    const int wave0 = blockIdx.x * WPB + wid;
    const int iters = (nrows + NWAVES - 1) / NWAVES;   // 32 at B=131072

    int row = wave0;
    // ---- prefetch row 0 ----
    float x0n = 0.f, x1n = 0.f;
    float4 w4n[4] = {};
    if (row < nrows) {
        x0n = inp[row * 128 + lane];
        x1n = inp[row * 128 + 64 + lane];
        const float4* wp = reinterpret_cast<const float4*>(gw) + row * 256;
        #pragma unroll
        for (int t = 0; t < 4; ++t) w4n[t] = wp[t * 64 + lane];
    }

    for (int it = 0; it < iters; ++it) {
        if (row >= nrows) break;
        const float x0 = x0n, x1 = x1n;
        float4 w4[4];
        #pragma unroll
        for (int t = 0; t < 4; ++t) w4[t] = w4n[t];

        // ---- prefetch next row (overlaps with compute below) ----
        const int nrow = row + NWAVES;
        if (it + 1 < iters && nrow < nrows) {
            x0n = inp[nrow * 128 + lane];
            x1n = inp[nrow * 128 + 64 + lane];
            const float4* wp = reinterpret_cast<const float4*>(gw) + nrow * 256;
            #pragma unroll
            for (int t = 0; t < 4; ++t) w4n[t] = wp[t * 64 + lane];
        }

        // ---- step 1: h = inp_row @ U -------------------------------------
        // lane accumulates h[4c..4c+3] (c = lane&7) over i = t*8+g, t=0..15
        float h1a[4] = {0.f, 0.f, 0.f, 0.f};
        #pragma unroll
        for (int t = 0; t < 16; ++t) {
            const float xs = (t < 8) ? x0 : x1;            // t is constant
            const float xi = __shfl(xs, (t & 7) * 8 + g, 64);
            const float4 u = u4s[t * 64 + lane];
            h1a[0] = fmaf(xi, u.x, h1a[0]);
            h1a[1] = fmaf(xi, u.y, h1a[1]);
            h1a[2] = fmaf(xi, u.z, h1a[2]);
            h1a[3] = fmaf(xi, u.w, h1a[3]);
        }
        #pragma unroll
        for (int s = 8; s <= 32; s <<= 1) {
            #pragma unroll
            for (int k = 0; k < 4; ++k)
                h1a[k] += __shfl_xor(h1a[k], s, 64);
        }
        // park h in per-wave LDS (lane group c holds h[4c..4c+3])
        if (lane < 8)
            reinterpret_cast<float4*>(hw)[lane] =
                make_float4(h1a[0], h1a[1], h1a[2], h1a[3]);

        // ---- step 2: h2 = h @ W_b ----------------------------------------
        float h2a[4] = {0.f, 0.f, 0.f, 0.f};
        #pragma unroll
        for (int t = 0; t < 4; ++t) {
            const float hi = hw[t * 8 + g];                // broadcast read
            h2a[0] = fmaf(hi, w4[t].x, h2a[0]);
            h2a[1] = fmaf(hi, w4[t].y, h2a[1]);
            h2a[2] = fmaf(hi, w4[t].z, h2a[2]);
            h2a[3] = fmaf(hi, w4[t].w, h2a[3]);
        }
        #pragma unroll
        for (int s = 8; s <= 32; s <<= 1) {
            #pragma unroll
            for (int k = 0; k < 4; ++k)
                h2a[k] += __shfl_xor(h2a[k], s, 64);
        }

        // ---- step 3: out_row = h2 @ V + bias -----------------------------
        // v_readlane (SALU path, constant lane index) instead of ds_bpermute:
        // keeps these 32 broadcasts OFF the LDS pipe.
        float o0 = b2.x, o1 = b2.y;
        #pragma unroll
        for (int r = 0; r < RANK; ++r) {
            const float h2r = bcast(h2a[r & 3], r >> 2);
            o0 = fmaf(h2r, v2[r].x, o0);
            o1 = fmaf(h2r, v2[r].y, o1);
        }
        reinterpret_cast<float2*>(out)[row * 64 + lane] = make_float2(o0, o1);

        row = nrow;
    }
}

extern "C" void kernel_launch(void* const* d_in, const int* in_sizes, int n_in,
                              void* d_out, int out_size, void* d_ws, size_t ws_size,
                              hipStream_t stream)
{
    const float* inp  = (const float*)d_in[0];
    const float* gw   = (const float*)d_in[1];
    const float* U    = (const float*)d_in[2];
    const float* V    = (const float*)d_in[3];
    const float* bias = (const float*)d_in[4];
    float* out = (float*)d_out;
    const int nrows = in_sizes[0] / 128;   // B = 131072

    apg_linear_kernel<<<GRID, BLOCK, 0, stream>>>(inp, gw, U, V, bias, out, nrows);
}

// Round 5
// 129.906 us; speedup vs baseline: 2.8826x; 1.0163x over previous
//
#include <hip/hip_runtime.h>

// APG_Linear: out[b] = ((inp[b] @ U) @ W_b) @ V + bias
//   B=131072, IN=128, OUT=128, RANK=32, all f32. Memory-bound (671 MB).
// R4 = R3 (132.0 us) with ONE change: the 24 __shfl_xor reduce ops/row
// (ds_swizzle/ds_bpermute -> LDS pipe) replaced by VALU-pipe cross-lane:
//   xor8  -> DPP row_ror:8            (v_add + dpp mov)
//   xor16 -> v_permlane16_swap_b32    (x+y of the returned pair)
//   xor32 -> v_permlane32_swap_b32
// Per-row LDS-pipe load ~390 -> ~246 cy, under the 478 cy/row HBM pace.
// Remaining LDS/row: 16 b128 U-reads + 16 bpermute x-bcasts + 5 park ops.

constexpr int RANK  = 32;
constexpr int BLOCK = 256;            // 4 waves/block
constexpr int WPB   = BLOCK / 64;
constexpr int GRID  = 1024;
constexpr int NWAVES = GRID * WPB;    // 4096 waves -> 32 rows/wave at B=131072

typedef int i2_t __attribute__((ext_vector_type(2)));

__device__ __forceinline__ float bcast(float v, int srclane) {
    return __uint_as_float(__builtin_amdgcn_readlane(__float_as_uint(v), srclane));
}

// --- VALU-pipe butterfly stages (keep these OFF the LDS pipe) ---
__device__ __forceinline__ float red_xor8(float v) {
#if __has_builtin(__builtin_amdgcn_update_dpp)
    // DPP row_ror:8 (0x128): lane l reads lane (l&~15)|((l+8)&15) == l^8
    int m = __builtin_amdgcn_update_dpp(0, __float_as_int(v), 0x128, 0xf, 0xf, true);
    return v + __int_as_float(m);
#else
    return v + __shfl_xor(v, 8, 64);
#endif
}

__device__ __forceinline__ float red_xor16(float v) {
#if __has_builtin(__builtin_amdgcn_permlane16_swap)
    // with src==dst: ret.x rows={r0,r0,r2,r2}, ret.y rows={r1,r1,r3,r3}
    // ret.x+ret.y == v[l] + v[l^16] for every lane
    i2_t r = __builtin_amdgcn_permlane16_swap(__float_as_int(v), __float_as_int(v),
                                              false, false);
    return __int_as_float(r.x) + __int_as_float(r.y);
#else
    return v + __shfl_xor(v, 16, 64);
#endif
}

__device__ __forceinline__ float red_xor32(float v) {
#if __has_builtin(__builtin_amdgcn_permlane32_swap)
    i2_t r = __builtin_amdgcn_permlane32_swap(__float_as_int(v), __float_as_int(v),
                                              false, false);
    return __int_as_float(r.x) + __int_as_float(r.y);
#else
    return v + __shfl_xor(v, 32, 64);
#endif
}

__device__ __forceinline__ float red_g(float v) {   // sum over lane bits 3,4,5
    return red_xor32(red_xor16(red_xor8(v)));
}

__global__ __launch_bounds__(BLOCK, 2)
void apg_linear_kernel(const float* __restrict__ inp,
                       const float* __restrict__ gw,
                       const float* __restrict__ U,
                       const float* __restrict__ V,
                       const float* __restrict__ bias,
                       float* __restrict__ out,
                       int nrows)
{
    __shared__ float4 u4s[1024];        // U staged: 128x32 f32 = 16 KiB
    __shared__ float  hbuf[WPB][RANK];  // per-wave h park (128 B each)

    const int tid  = threadIdx.x;
    const int lane = tid & 63;
    const int wid  = tid >> 6;
    const int g    = lane >> 3;         // 0..7

    // ---- stage U into LDS (flat float4 layout: u4s[f] = U[4f..4f+3]) ----
    #pragma unroll
    for (int j = 0; j < 4; ++j)
        u4s[j * BLOCK + tid] = reinterpret_cast<const float4*>(U)[j * BLOCK + tid];
    __syncthreads();

    // ---- V and bias in registers: lane owns output cols {2*lane, 2*lane+1} ----
    float2 v2[RANK];
    #pragma unroll
    for (int r = 0; r < RANK; ++r)
        v2[r] = reinterpret_cast<const float2*>(V + r * 128)[lane];
    const float2 b2 = reinterpret_cast<const float2*>(bias)[lane];

    float* hw = hbuf[wid];

    const int wave0 = blockIdx.x * WPB + wid;
    const int iters = (nrows + NWAVES - 1) / NWAVES;   // 32 at B=131072

    int row = wave0;
    // ---- prefetch row 0 ----
    float x0n = 0.f, x1n = 0.f;
    float4 w4n[4] = {};
    if (row < nrows) {
        x0n = inp[row * 128 + lane];
        x1n = inp[row * 128 + 64 + lane];
        const float4* wp = reinterpret_cast<const float4*>(gw) + row * 256;
        #pragma unroll
        for (int t = 0; t < 4; ++t) w4n[t] = wp[t * 64 + lane];
    }

    for (int it = 0; it < iters; ++it) {
        if (row >= nrows) break;
        const float x0 = x0n, x1 = x1n;
        float4 w4[4];
        #pragma unroll
        for (int t = 0; t < 4; ++t) w4[t] = w4n[t];

        // ---- prefetch next row (overlaps with compute below) ----
        const int nrow = row + NWAVES;
        if (it + 1 < iters && nrow < nrows) {
            x0n = inp[nrow * 128 + lane];
            x1n = inp[nrow * 128 + 64 + lane];
            const float4* wp = reinterpret_cast<const float4*>(gw) + nrow * 256;
            #pragma unroll
            for (int t = 0; t < 4; ++t) w4n[t] = wp[t * 64 + lane];
        }

        // ---- step 1: h = inp_row @ U -------------------------------------
        // lane accumulates h[4c..4c+3] (c = lane&7) over i = t*8+g, t=0..15
        float h1a[4] = {0.f, 0.f, 0.f, 0.f};
        #pragma unroll
        for (int t = 0; t < 16; ++t) {
            const float xs = (t < 8) ? x0 : x1;            // t is constant
            const float xi = __shfl(xs, (t & 7) * 8 + g, 64);
            const float4 u = u4s[t * 64 + lane];
            h1a[0] = fmaf(xi, u.x, h1a[0]);
            h1a[1] = fmaf(xi, u.y, h1a[1]);
            h1a[2] = fmaf(xi, u.z, h1a[2]);
            h1a[3] = fmaf(xi, u.w, h1a[3]);
        }
        #pragma unroll
        for (int k = 0; k < 4; ++k) h1a[k] = red_g(h1a[k]);   // VALU butterfly
        // park h in per-wave LDS (lane group c holds h[4c..4c+3])
        if (lane < 8)
            reinterpret_cast<float4*>(hw)[lane] =
                make_float4(h1a[0], h1a[1], h1a[2], h1a[3]);

        // ---- step 2: h2 = h @ W_b ----------------------------------------
        float h2a[4] = {0.f, 0.f, 0.f, 0.f};
        #pragma unroll
        for (int t = 0; t < 4; ++t) {
            const float hi = hw[t * 8 + g];                // broadcast read
            h2a[0] = fmaf(hi, w4[t].x, h2a[0]);
            h2a[1] = fmaf(hi, w4[t].y, h2a[1]);
            h2a[2] = fmaf(hi, w4[t].z, h2a[2]);
            h2a[3] = fmaf(hi, w4[t].w, h2a[3]);
        }
        #pragma unroll
        for (int k = 0; k < 4; ++k) h2a[k] = red_g(h2a[k]);   // VALU butterfly

        // ---- step 3: out_row = h2 @ V + bias (readlane broadcasts) -------
        float o0 = b2.x, o1 = b2.y;
        #pragma unroll
        for (int r = 0; r < RANK; ++r) {
            const float h2r = bcast(h2a[r & 3], r >> 2);
            o0 = fmaf(h2r, v2[r].x, o0);
            o1 = fmaf(h2r, v2[r].y, o1);
        }
        reinterpret_cast<float2*>(out)[row * 64 + lane] = make_float2(o0, o1);

        row = nrow;
    }
}

extern "C" void kernel_launch(void* const* d_in, const int* in_sizes, int n_in,
                              void* d_out, int out_size, void* d_ws, size_t ws_size,
                              hipStream_t stream)
{
    const float* inp  = (const float*)d_in[0];
    const float* gw   = (const float*)d_in[1];
    const float* U    = (const float*)d_in[2];
    const float* V    = (const float*)d_in[3];
    const float* bias = (const float*)d_in[4];
    float* out = (float*)d_out;
    const int nrows = in_sizes[0] / 128;   // B = 131072

    apg_linear_kernel<<<GRID, BLOCK, 0, stream>>>(inp, gw, U, V, bias, out, nrows);
}